// Round 5
// baseline (222.313 us; speedup 1.0000x reference)
//
#include <hip/hip_runtime.h>
#include <hip/hip_fp16.h>

// out = sa*sb * (x @ q_b) @ q_a^T + bias
// GEMM1 (split-K): partials[z] = x[:, z-chunk] @ q_b[z-chunk]   (f32 partials)
// reduce: t = fp16(sum_z partials[z])
// GEMM2: out = t @ q_a^T * scale + bias
// Round 5: split-K to break the TLP cap (N=512 -> only 1024 blocks without it).
// GEMM1 body = round-3 measured-best simple 2-barrier structure, unchanged.

#define M_TOT 8192
#define N_OUT 4096
#define K_IN  4096
#define RANK  512

typedef _Float16 f16x8 __attribute__((ext_vector_type(8)));
typedef float f32x4 __attribute__((ext_vector_type(4)));

#define WAIT_VM0() asm volatile("s_waitcnt vmcnt(0)" ::: "memory")
#define WAIT_VM8() asm volatile("s_waitcnt vmcnt(8)" ::: "memory")
#define BARRIER() do { __builtin_amdgcn_s_barrier(); __builtin_amdgcn_sched_barrier(0); } while (0)

__device__ __forceinline__ void gload_lds16(const void* g, void* l) {
  __builtin_amdgcn_global_load_lds(
      (const __attribute__((address_space(1))) unsigned int*)g,
      (__attribute__((address_space(3))) unsigned int*)l, 16, 0, 0);
}

// ---- convert q_a int32 -> fp16, same [OUT][RANK] layout ----
__global__ void k_cvt_qa(const int4* __restrict__ q, ushort4* __restrict__ o, int n4) {
  int i = blockIdx.x * blockDim.x + threadIdx.x;
  if (i >= n4) return;
  int4 v = q[i];
  ushort4 r;
  r.x = __half_as_ushort(__float2half_rn((float)v.x));
  r.y = __half_as_ushort(__float2half_rn((float)v.y));
  r.z = __half_as_ushort(__float2half_rn((float)v.z));
  r.w = __half_as_ushort(__float2half_rn((float)v.w));
  o[i] = r;
}

// ---- transpose q_b [K_IN][RANK] i32 -> qbt [RANK][K_IN] fp16 ----
__global__ void k_transpose_qb(const int* __restrict__ qb, __half* __restrict__ qbt) {
  __shared__ __half tile[32][33];
  int tx = threadIdx.x & 31, ty = threadIdx.x >> 5;
  int k0 = blockIdx.x * 32, r0 = blockIdx.y * 32;
#pragma unroll
  for (int j = 0; j < 4; ++j)
    tile[ty + j * 8][tx] = __float2half_rn((float)qb[(size_t)(k0 + ty + j * 8) * RANK + r0 + tx]);
  __syncthreads();
#pragma unroll
  for (int j = 0; j < 4; ++j)
    qbt[(size_t)(r0 + ty + j * 8) * K_IN + k0 + tx] = tile[tx][ty + j * 8];
}

// ---- GEMM1 split-K: P[z] = X[:, z*KCH:(z+1)*KCH] @ qbt[:, same]^T ----
// BM=64 BN=64 BK=64, 4 waves (2m x 2n), wave tile 32x32, acc[2][2].
// Round-3 body; grid (M/64, 8, SK); f32 partial epilogue; 8 blocks/CU target.
template <int SK>
__global__ __launch_bounds__(256, 8) void k_gemm1_sk(
    const float* __restrict__ X, const __half* __restrict__ Bt,
    float* __restrict__ P) {
  __shared__ __align__(16) uint4 lds[1024];  // [0,512)=A 64x8, [512,1024)=B 64x8
  const int tid = threadIdx.x;
  const int lane = tid & 63, wid = tid >> 6, wm = wid & 1, wn = wid >> 1;
  const int m0 = blockIdx.x * 64, n0 = blockIdx.y * 64;
  const int kbeg = blockIdx.z * (K_IN / SK);
  const int kend = kbeg + (K_IN / SK);
  const int fr = lane & 15, fq = lane >> 4;

  f32x4 acc[2][2] = {};

  const int ar = tid >> 2, aq = tid & 3;
  const float* xbase = X + (size_t)(m0 + ar) * K_IN + aq * 16;
  const int bd0 = tid, bd1 = tid + 256;
  const __half* bsrc0 = Bt + (size_t)(n0 + (bd0 >> 3)) * K_IN + ((bd0 & 7) ^ ((bd0 >> 3) & 7)) * 8;
  const __half* bsrc1 = Bt + (size_t)(n0 + (bd1 >> 3)) * K_IN + ((bd1 & 7) ^ ((bd1 >> 3) & 7)) * 8;

  for (int k0 = kbeg; k0 < kend; k0 += 64) {
    gload_lds16(bsrc0 + k0, &lds[512 + bd0]);
    gload_lds16(bsrc1 + k0, &lds[512 + bd1]);
    float4 v0 = *(const float4*)(xbase + k0);
    float4 v1 = *(const float4*)(xbase + k0 + 4);
    float4 v2 = *(const float4*)(xbase + k0 + 8);
    float4 v3 = *(const float4*)(xbase + k0 + 12);
    union { __half2 h[4]; uint4 u; } p0, p1;
    p0.h[0] = __floats2half2_rn(v0.x, v0.y);
    p0.h[1] = __floats2half2_rn(v0.z, v0.w);
    p0.h[2] = __floats2half2_rn(v1.x, v1.y);
    p0.h[3] = __floats2half2_rn(v1.z, v1.w);
    p1.h[0] = __floats2half2_rn(v2.x, v2.y);
    p1.h[1] = __floats2half2_rn(v2.z, v2.w);
    p1.h[2] = __floats2half2_rn(v3.x, v3.y);
    p1.h[3] = __floats2half2_rn(v3.z, v3.w);
    lds[ar * 8 + ((2 * aq) ^ (ar & 7))] = p0.u;
    lds[ar * 8 + ((2 * aq + 1) ^ (ar & 7))] = p1.u;
    __syncthreads();
    f16x8 a[2][2], b[2][2];
#pragma unroll
    for (int kk = 0; kk < 2; ++kk) {
      int s = kk * 4 + fq;
#pragma unroll
      for (int mi = 0; mi < 2; ++mi) {
        int r = wm * 32 + mi * 16 + fr;
        a[mi][kk] = *(const f16x8*)&lds[r * 8 + (s ^ (r & 7))];
      }
#pragma unroll
      for (int ni = 0; ni < 2; ++ni) {
        int n = wn * 32 + ni * 16 + fr;
        b[ni][kk] = *(const f16x8*)&lds[512 + n * 8 + (s ^ (n & 7))];
      }
    }
#pragma unroll
    for (int kk = 0; kk < 2; ++kk)
#pragma unroll
      for (int mi = 0; mi < 2; ++mi)
#pragma unroll
        for (int ni = 0; ni < 2; ++ni)
          acc[mi][ni] = __builtin_amdgcn_mfma_f32_16x16x32_f16(a[mi][kk], b[ni][kk], acc[mi][ni], 0, 0, 0);
    __syncthreads();
  }

  float* Pz = P + (size_t)blockIdx.z * M_TOT * RANK;
#pragma unroll
  for (int mi = 0; mi < 2; ++mi)
#pragma unroll
    for (int ni = 0; ni < 2; ++ni) {
      int col = n0 + wn * 32 + ni * 16 + fr;
      int rbase = m0 + wm * 32 + mi * 16 + fq * 4;
#pragma unroll
      for (int j = 0; j < 4; ++j)
        Pz[(size_t)(rbase + j) * RANK + col] = acc[mi][ni][j];
    }
}

// ---- direct fallback (round-3 kernel): t fp16 written straight ----
__global__ __launch_bounds__(256, 4) void k_gemm1_direct(
    const float* __restrict__ X, const __half* __restrict__ Bt,
    __half* __restrict__ T) {
  __shared__ __align__(16) uint4 lds[1024];
  const int tid = threadIdx.x;
  const int lane = tid & 63, wid = tid >> 6, wm = wid & 1, wn = wid >> 1;
  const int m0 = blockIdx.x * 64, n0 = blockIdx.y * 64;
  const int fr = lane & 15, fq = lane >> 4;
  f32x4 acc[2][2] = {};
  const int ar = tid >> 2, aq = tid & 3;
  const float* xbase = X + (size_t)(m0 + ar) * K_IN + aq * 16;
  const int bd0 = tid, bd1 = tid + 256;
  const __half* bsrc0 = Bt + (size_t)(n0 + (bd0 >> 3)) * K_IN + ((bd0 & 7) ^ ((bd0 >> 3) & 7)) * 8;
  const __half* bsrc1 = Bt + (size_t)(n0 + (bd1 >> 3)) * K_IN + ((bd1 & 7) ^ ((bd1 >> 3) & 7)) * 8;
  for (int k0 = 0; k0 < K_IN; k0 += 64) {
    gload_lds16(bsrc0 + k0, &lds[512 + bd0]);
    gload_lds16(bsrc1 + k0, &lds[512 + bd1]);
    float4 v0 = *(const float4*)(xbase + k0);
    float4 v1 = *(const float4*)(xbase + k0 + 4);
    float4 v2 = *(const float4*)(xbase + k0 + 8);
    float4 v3 = *(const float4*)(xbase + k0 + 12);
    union { __half2 h[4]; uint4 u; } p0, p1;
    p0.h[0] = __floats2half2_rn(v0.x, v0.y);
    p0.h[1] = __floats2half2_rn(v0.z, v0.w);
    p0.h[2] = __floats2half2_rn(v1.x, v1.y);
    p0.h[3] = __floats2half2_rn(v1.z, v1.w);
    p1.h[0] = __floats2half2_rn(v2.x, v2.y);
    p1.h[1] = __floats2half2_rn(v2.z, v2.w);
    p1.h[2] = __floats2half2_rn(v3.x, v3.y);
    p1.h[3] = __floats2half2_rn(v3.z, v3.w);
    lds[ar * 8 + ((2 * aq) ^ (ar & 7))] = p0.u;
    lds[ar * 8 + ((2 * aq + 1) ^ (ar & 7))] = p1.u;
    __syncthreads();
    f16x8 a[2][2], b[2][2];
#pragma unroll
    for (int kk = 0; kk < 2; ++kk) {
      int s = kk * 4 + fq;
#pragma unroll
      for (int mi = 0; mi < 2; ++mi) {
        int r = wm * 32 + mi * 16 + fr;
        a[mi][kk] = *(const f16x8*)&lds[r * 8 + (s ^ (r & 7))];
      }
#pragma unroll
      for (int ni = 0; ni < 2; ++ni) {
        int n = wn * 32 + ni * 16 + fr;
        b[ni][kk] = *(const f16x8*)&lds[512 + n * 8 + (s ^ (n & 7))];
      }
    }
#pragma unroll
    for (int kk = 0; kk < 2; ++kk)
#pragma unroll
      for (int mi = 0; mi < 2; ++mi)
#pragma unroll
        for (int ni = 0; ni < 2; ++ni)
          acc[mi][ni] = __builtin_amdgcn_mfma_f32_16x16x32_f16(a[mi][kk], b[ni][kk], acc[mi][ni], 0, 0, 0);
    __syncthreads();
  }
#pragma unroll
  for (int mi = 0; mi < 2; ++mi)
#pragma unroll
    for (int ni = 0; ni < 2; ++ni) {
      int col = n0 + wn * 32 + ni * 16 + fr;
      int rbase = m0 + wm * 32 + mi * 16 + fq * 4;
#pragma unroll
      for (int j = 0; j < 4; ++j)
        T[(size_t)(rbase + j) * RANK + col] = __float2half_rn(acc[mi][ni][j]);
    }
}

// ---- reduce: t = fp16(sum_z P[z]) ----
template <int SK>
__global__ void k_reduce_t(const float4* __restrict__ P, ushort4* __restrict__ T4, int n4) {
  int i = blockIdx.x * blockDim.x + threadIdx.x;
  if (i >= n4) return;
  float4 s = P[i];
#pragma unroll
  for (int z = 1; z < SK; ++z) {
    float4 v = P[(size_t)z * n4 + i];
    s.x += v.x; s.y += v.y; s.z += v.z; s.w += v.w;
  }
  ushort4 r;
  r.x = __half_as_ushort(__float2half_rn(s.x));
  r.y = __half_as_ushort(__float2half_rn(s.y));
  r.z = __half_as_ushort(__float2half_rn(s.z));
  r.w = __half_as_ushort(__float2half_rn(s.w));
  T4[i] = r;
}

// ---- GEMM2: out = t @ qa^T * scale + bias (M=8192, N=4096, K=512) ----
// BM=128 BN=128 BK=64, 4 waves (2x2), wave tile 64x64, acc[4][4].
// Pure gload_lds both operands, counted vmcnt(8) dbuf. (round-4 version)
__global__ __launch_bounds__(256, 2) void k_gemm2(
    const __half* __restrict__ T, const __half* __restrict__ QA,
    const float* __restrict__ sa, const float* __restrict__ sb,
    const float* __restrict__ bias, float* __restrict__ Out) {
  __shared__ __align__(16) uint4 lds[2][2048];
  const int tid = threadIdx.x;
  const int lane = tid & 63, wid = tid >> 6, wm = wid & 1, wn = wid >> 1;
  const int m0 = blockIdx.x * 128, n0 = blockIdx.y * 128;
  const int fr = lane & 15, fq = lane >> 4;

  f32x4 acc[4][4] = {};

  auto stage = [&](int kt, int buf) {
#pragma unroll
    for (int c = 0; c < 4; ++c) {
      int d = tid + 256 * c;
      int r = d >> 3, s = (d & 7) ^ (r & 7);
      gload_lds16(T + (size_t)(m0 + r) * RANK + kt * 64 + s * 8, &lds[buf][d]);
    }
#pragma unroll
    for (int c = 0; c < 4; ++c) {
      int d = tid + 256 * c;
      int r = d >> 3, s = (d & 7) ^ (r & 7);
      gload_lds16(QA + (size_t)(n0 + r) * RANK + kt * 64 + s * 8, &lds[buf][1024 + d]);
    }
  };

  stage(0, 0);
  stage(1, 1);
  WAIT_VM8();
  BARRIER();

  const int NT = RANK / 64;
  for (int t = 0; t < NT; ++t) {
    const int cur = t & 1;
#pragma unroll
    for (int kk = 0; kk < 2; ++kk) {
      int s = kk * 4 + fq;
      f16x8 a[4], b[4];
#pragma unroll
      for (int mi = 0; mi < 4; ++mi) {
        int r = wm * 64 + mi * 16 + fr;
        a[mi] = *(const f16x8*)&lds[cur][r * 8 + (s ^ (r & 7))];
      }
#pragma unroll
      for (int ni = 0; ni < 4; ++ni) {
        int n = wn * 64 + ni * 16 + fr;
        b[ni] = *(const f16x8*)&lds[cur][1024 + n * 8 + (s ^ (n & 7))];
      }
#pragma unroll
      for (int mi = 0; mi < 4; ++mi)
#pragma unroll
        for (int ni = 0; ni < 4; ++ni)
          acc[mi][ni] = __builtin_amdgcn_mfma_f32_16x16x32_f16(a[mi], b[ni], acc[mi][ni], 0, 0, 0);
    }
    if (t == NT - 1) break;
    BARRIER();
    if (t + 2 < NT) {
      stage(t + 2, cur);
      WAIT_VM8();
    } else {
      WAIT_VM0();
    }
    BARRIER();
  }

  const float scale = sa[0] * sb[0];
#pragma unroll
  for (int mi = 0; mi < 4; ++mi)
#pragma unroll
    for (int ni = 0; ni < 4; ++ni) {
      int col = n0 + wn * 64 + ni * 16 + fr;
      float bv = bias[col];
      int rbase = m0 + wm * 64 + mi * 16 + fq * 4;
#pragma unroll
      for (int j = 0; j < 4; ++j)
        Out[(size_t)(rbase + j) * N_OUT + col] = acc[mi][ni][j] * scale + bv;
    }
}

extern "C" void kernel_launch(void* const* d_in, const int* in_sizes, int n_in,
                              void* d_out, int out_size, void* d_ws, size_t ws_size,
                              hipStream_t stream) {
  const float* x    = (const float*)d_in[0];
  const int*   qa   = (const int*)d_in[1];
  const int*   qb   = (const int*)d_in[2];
  const float* sa   = (const float*)d_in[3];
  const float* sb   = (const float*)d_in[4];
  const float* bias = (const float*)d_in[5];
  float* out = (float*)d_out;

  char* ws = (char*)d_ws;
  __half* qa_h = (__half*)ws;                  // 4 MB
  __half* qbt  = (__half*)(ws + (4u << 20));   // 4 MB
  __half* t    = (__half*)(ws + (8u << 20));   // 8 MB
  float*  part = (float*)(ws + (16u << 20));   // SK * 16 MB

  k_cvt_qa<<<2048, 256, 0, stream>>>((const int4*)qa, (ushort4*)qa_h, (N_OUT * RANK) / 4);
  dim3 tg(K_IN / 32, RANK / 32);
  k_transpose_qb<<<tg, 256, 0, stream>>>(qb, qbt);

  const int n4 = M_TOT * RANK / 4;  // 1,048,576
  if (ws_size >= (80ull << 20)) {
    dim3 g1(M_TOT / 64, RANK / 64, 4);
    k_gemm1_sk<4><<<g1, 256, 0, stream>>>(x, qbt, part);
    k_reduce_t<4><<<(n4 + 255) / 256, 256, 0, stream>>>((const float4*)part, (ushort4*)t, n4);
  } else if (ws_size >= (48ull << 20)) {
    dim3 g1(M_TOT / 64, RANK / 64, 2);
    k_gemm1_sk<2><<<g1, 256, 0, stream>>>(x, qbt, part);
    k_reduce_t<2><<<(n4 + 255) / 256, 256, 0, stream>>>((const float4*)part, (ushort4*)t, n4);
  } else {
    dim3 g1(M_TOT / 64, RANK / 64);
    k_gemm1_direct<<<g1, 256, 0, stream>>>(x, qbt, t);
  }

  dim3 g2(M_TOT / 128, N_OUT / 128);
  k_gemm2<<<g2, 256, 0, stream>>>(t, qa_h, sa, sb, bias, out);
}

// Round 6
// 137.621 us; speedup vs baseline: 1.6154x; 1.6154x over previous
//
#include <hip/hip_runtime.h>
#include <hip/hip_fp16.h>

// out = sa*sb * (x @ q_b) @ q_a^T + bias
// GEMM1 (split-K=4): P[z] = x[:, z*1024:+1024] @ q_b-chunk   (f16 partials)
//   BM=64 BN=256 BK=64, 4 waves each 64x64, grid 1024 = 4 blocks/CU resident.
// reduce: t = f16(sum_z P[z])
// GEMM2: out = t @ q_a^T * scale + bias (128x128x64, counted-vmcnt dbuf)
// Round 6: minimize cache-delivered staged bytes (the measured ~11 TB/s
// ceiling across R3/R4/R5): big BN cuts x re-stages 8x->2x; XCD-chunked
// swizzle keeps qbt z-slice (1 MB) and x n-partners L2-local.

#define M_TOT 8192
#define N_OUT 4096
#define K_IN  4096
#define RANK  512

typedef _Float16 f16x8 __attribute__((ext_vector_type(8)));
typedef float f32x4 __attribute__((ext_vector_type(4)));

#define WAIT_VM0() asm volatile("s_waitcnt vmcnt(0)" ::: "memory")
#define WAIT_VM8() asm volatile("s_waitcnt vmcnt(8)" ::: "memory")
#define BARRIER() do { __builtin_amdgcn_s_barrier(); __builtin_amdgcn_sched_barrier(0); } while (0)

__device__ __forceinline__ void gload_lds16(const void* g, void* l) {
  __builtin_amdgcn_global_load_lds(
      (const __attribute__((address_space(1))) unsigned int*)g,
      (__attribute__((address_space(3))) unsigned int*)l, 16, 0, 0);
}

// ---- convert q_a int32 -> fp16, same [OUT][RANK] layout ----
__global__ void k_cvt_qa(const int4* __restrict__ q, ushort4* __restrict__ o, int n4) {
  int i = blockIdx.x * blockDim.x + threadIdx.x;
  if (i >= n4) return;
  int4 v = q[i];
  ushort4 r;
  r.x = __half_as_ushort(__float2half_rn((float)v.x));
  r.y = __half_as_ushort(__float2half_rn((float)v.y));
  r.z = __half_as_ushort(__float2half_rn((float)v.z));
  r.w = __half_as_ushort(__float2half_rn((float)v.w));
  o[i] = r;
}

// ---- transpose q_b [K_IN][RANK] i32 -> qbt [RANK][K_IN] fp16 ----
__global__ void k_transpose_qb(const int* __restrict__ qb, __half* __restrict__ qbt) {
  __shared__ __half tile[32][33];
  int tx = threadIdx.x & 31, ty = threadIdx.x >> 5;
  int k0 = blockIdx.x * 32, r0 = blockIdx.y * 32;
#pragma unroll
  for (int j = 0; j < 4; ++j)
    tile[ty + j * 8][tx] = __float2half_rn((float)qb[(size_t)(k0 + ty + j * 8) * RANK + r0 + tx]);
  __syncthreads();
#pragma unroll
  for (int j = 0; j < 4; ++j)
    qbt[(size_t)(r0 + ty + j * 8) * K_IN + k0 + tx] = tile[tx][ty + j * 8];
}

// ---- GEMM1 split-K: P[z] = X[:, z-chunk] @ qbt[:, z-chunk]^T ----
// BM=64 BN=256 BK=64; 4 waves, each computing the full 64 m-rows x its own
// 64 n-cols (acc[4][4]). A reg-staged f32->f16; B 8x gload_lds (32 KB).
// LDS 40 KB single-buffer -> 4 blocks/CU; grid 1024 fully resident.
// XCD-chunk mapping: xcd = flat&7 owns (z = xcd>>1, m-half = xcd&1);
// within: n-partner blocks adjacent (x panel shared in L2).
__global__ __launch_bounds__(256, 4) void k_gemm1_sk(
    const float* __restrict__ X, const __half* __restrict__ Bt,
    __half* __restrict__ P) {
  __shared__ __align__(16) uint4 lds[2560];  // [0,512)=A 64x8, [512,2560)=B 256x8
  const int tid = threadIdx.x;
  const int lane = tid & 63, wn = tid >> 6;          // 4 waves split N only
  const int flat = blockIdx.x;
  const int xcd = flat & 7, local = flat >> 3;        // local 0..127
  const int z = xcd >> 1;                             // 0..3
  const int m_t = (xcd & 1) * 64 + (local >> 1);      // 0..127
  const int n_t = local & 1;                          // 0..1
  const int m0 = m_t * 64, n0 = n_t * 256;
  const int kbeg = z * (K_IN / 4);
  const int fr = lane & 15, fq = lane >> 4;

  f32x4 acc[4][4] = {};

  // A stage: thread -> row ar = tid>>2 (0..63), quarter aq (16 floats -> 2 slots)
  const int ar = tid >> 2, aq = tid & 3;
  const float* xbase = X + (size_t)(m0 + ar) * K_IN + aq * 16;
  const int aslot0 = ar * 8 + ((2 * aq) ^ (ar & 7));
  const int aslot1 = ar * 8 + ((2 * aq + 1) ^ (ar & 7));

  for (int it = 0; it < (K_IN / 4) / 64; ++it) {
    const int k0 = kbeg + it * 64;
    // B stage: 8 gload_lds, linear dest slot, swizzled source col
#pragma unroll
    for (int c = 0; c < 8; ++c) {
      int d = tid + 256 * c;
      int r = d >> 3, s = (d & 7) ^ (r & 7);
      gload_lds16(Bt + (size_t)(n0 + r) * K_IN + k0 + s * 8, &lds[512 + d]);
    }
    float4 v0 = *(const float4*)(xbase + k0);
    float4 v1 = *(const float4*)(xbase + k0 + 4);
    float4 v2 = *(const float4*)(xbase + k0 + 8);
    float4 v3 = *(const float4*)(xbase + k0 + 12);
    union { __half2 h[4]; uint4 u; } p0, p1;
    p0.h[0] = __floats2half2_rn(v0.x, v0.y);
    p0.h[1] = __floats2half2_rn(v0.z, v0.w);
    p0.h[2] = __floats2half2_rn(v1.x, v1.y);
    p0.h[3] = __floats2half2_rn(v1.z, v1.w);
    p1.h[0] = __floats2half2_rn(v2.x, v2.y);
    p1.h[1] = __floats2half2_rn(v2.z, v2.w);
    p1.h[2] = __floats2half2_rn(v3.x, v3.y);
    p1.h[3] = __floats2half2_rn(v3.z, v3.w);
    lds[aslot0] = p0.u;
    lds[aslot1] = p1.u;
    __syncthreads();
#pragma unroll
    for (int kk = 0; kk < 2; ++kk) {
      const int s = kk * 4 + fq;
      f16x8 a[4], b[4];
#pragma unroll
      for (int mi = 0; mi < 4; ++mi) {
        int r = mi * 16 + fr;
        a[mi] = *(const f16x8*)&lds[r * 8 + (s ^ (r & 7))];
      }
#pragma unroll
      for (int ni = 0; ni < 4; ++ni) {
        int n = wn * 64 + ni * 16 + fr;
        b[ni] = *(const f16x8*)&lds[512 + n * 8 + (s ^ (n & 7))];
      }
#pragma unroll
      for (int mi = 0; mi < 4; ++mi)
#pragma unroll
        for (int ni = 0; ni < 4; ++ni)
          acc[mi][ni] = __builtin_amdgcn_mfma_f32_16x16x32_f16(a[mi], b[ni], acc[mi][ni], 0, 0, 0);
    }
    __syncthreads();
  }

  __half* Pz = P + (size_t)z * M_TOT * RANK;
#pragma unroll
  for (int mi = 0; mi < 4; ++mi)
#pragma unroll
    for (int ni = 0; ni < 4; ++ni) {
      int col = n0 + wn * 64 + ni * 16 + fr;
      int rbase = m0 + mi * 16 + fq * 4;
#pragma unroll
      for (int j = 0; j < 4; ++j)
        Pz[(size_t)(rbase + j) * RANK + col] = __float2half_rn(acc[mi][ni][j]);
    }
}

// ---- reduce: t = f16(sum_z P[z]), f32 math, 8 halfs/thread ----
__global__ void k_reduce_t(const uint4* __restrict__ P, uint4* __restrict__ T8, int n8) {
  int i = blockIdx.x * blockDim.x + threadIdx.x;
  if (i >= n8) return;
  float2 f[4] = {};
#pragma unroll
  for (int zz = 0; zz < 4; ++zz) {
    uint4 v = P[(size_t)zz * n8 + i];
    const __half2* h = (const __half2*)&v;
#pragma unroll
    for (int j = 0; j < 4; ++j) {
      float2 g = __half22float2(h[j]);
      f[j].x += g.x; f[j].y += g.y;
    }
  }
  uint4 r;
  __half2* o = (__half2*)&r;
#pragma unroll
  for (int j = 0; j < 4; ++j) o[j] = __floats2half2_rn(f[j].x, f[j].y);
  T8[i] = r;
}

// ---- GEMM2: out = t @ qa^T * scale + bias (M=8192, N=4096, K=512) ----
// BM=128 BN=128 BK=64, 4 waves (2x2), wave tile 64x64, acc[4][4].
// Counted vmcnt(8) dbuf (round-4 proven). Flat grid + XCD-chunk swizzle:
// each XCD owns 4 n-tiles (qa panels 512 KB L2-hot), t-panel consumers adjacent.
__global__ __launch_bounds__(256, 2) void k_gemm2(
    const __half* __restrict__ T, const __half* __restrict__ QA,
    const float* __restrict__ sa, const float* __restrict__ sb,
    const float* __restrict__ bias, float* __restrict__ Out) {
  __shared__ __align__(16) uint4 lds[2][2048];
  const int tid = threadIdx.x;
  const int lane = tid & 63, wid = tid >> 6, wm = wid & 1, wn = wid >> 1;
  const int flat = blockIdx.x;
  const int xcd = flat & 7, local = flat >> 3;        // local 0..255
  const int n_t = xcd * 4 + (local & 3);              // 0..31
  const int m_t = local >> 2;                         // 0..63
  const int m0 = m_t * 128, n0 = n_t * 128;
  const int fr = lane & 15, fq = lane >> 4;

  f32x4 acc[4][4] = {};

  auto stage = [&](int kt, int buf) {
#pragma unroll
    for (int c = 0; c < 4; ++c) {
      int d = tid + 256 * c;
      int r = d >> 3, s = (d & 7) ^ (r & 7);
      gload_lds16(T + (size_t)(m0 + r) * RANK + kt * 64 + s * 8, &lds[buf][d]);
    }
#pragma unroll
    for (int c = 0; c < 4; ++c) {
      int d = tid + 256 * c;
      int r = d >> 3, s = (d & 7) ^ (r & 7);
      gload_lds16(QA + (size_t)(n0 + r) * RANK + kt * 64 + s * 8, &lds[buf][1024 + d]);
    }
  };

  stage(0, 0);
  stage(1, 1);
  WAIT_VM8();
  BARRIER();

  const int NT = RANK / 64;
  for (int t = 0; t < NT; ++t) {
    const int cur = t & 1;
#pragma unroll
    for (int kk = 0; kk < 2; ++kk) {
      int s = kk * 4 + fq;
      f16x8 a[4], b[4];
#pragma unroll
      for (int mi = 0; mi < 4; ++mi) {
        int r = wm * 64 + mi * 16 + fr;
        a[mi] = *(const f16x8*)&lds[cur][r * 8 + (s ^ (r & 7))];
      }
#pragma unroll
      for (int ni = 0; ni < 4; ++ni) {
        int n = wn * 64 + ni * 16 + fr;
        b[ni] = *(const f16x8*)&lds[cur][1024 + n * 8 + (s ^ (n & 7))];
      }
#pragma unroll
      for (int mi = 0; mi < 4; ++mi)
#pragma unroll
        for (int ni = 0; ni < 4; ++ni)
          acc[mi][ni] = __builtin_amdgcn_mfma_f32_16x16x32_f16(a[mi], b[ni], acc[mi][ni], 0, 0, 0);
    }
    if (t == NT - 1) break;
    BARRIER();
    if (t + 2 < NT) {
      stage(t + 2, cur);
      WAIT_VM8();
    } else {
      WAIT_VM0();
    }
    BARRIER();
  }

  const float scale = sa[0] * sb[0];
#pragma unroll
  for (int mi = 0; mi < 4; ++mi)
#pragma unroll
    for (int ni = 0; ni < 4; ++ni) {
      int col = n0 + wn * 64 + ni * 16 + fr;
      float bv = bias[col];
      int rbase = m0 + wm * 64 + mi * 16 + fq * 4;
#pragma unroll
      for (int j = 0; j < 4; ++j)
        Out[(size_t)(rbase + j) * N_OUT + col] = acc[mi][ni][j] * scale + bv;
    }
}

extern "C" void kernel_launch(void* const* d_in, const int* in_sizes, int n_in,
                              void* d_out, int out_size, void* d_ws, size_t ws_size,
                              hipStream_t stream) {
  const float* x    = (const float*)d_in[0];
  const int*   qa   = (const int*)d_in[1];
  const int*   qb   = (const int*)d_in[2];
  const float* sa   = (const float*)d_in[3];
  const float* sb   = (const float*)d_in[4];
  const float* bias = (const float*)d_in[5];
  float* out = (float*)d_out;

  char* ws = (char*)d_ws;
  __half* qa_h = (__half*)ws;                  // 4 MB
  __half* qbt  = (__half*)(ws + (4u << 20));   // 4 MB
  __half* t    = (__half*)(ws + (8u << 20));   // 8 MB
  __half* part = (__half*)(ws + (16u << 20));  // 4 x 8 MB f16 partials

  k_cvt_qa<<<2048, 256, 0, stream>>>((const int4*)qa, (ushort4*)qa_h, (N_OUT * RANK) / 4);
  dim3 tg(K_IN / 32, RANK / 32);
  k_transpose_qb<<<tg, 256, 0, stream>>>(qb, qbt);

  k_gemm1_sk<<<1024, 256, 0, stream>>>(x, qbt, part);
  const int n8 = M_TOT * RANK / 8;  // 524288
  k_reduce_t<<<n8 / 256, 256, 0, stream>>>((const uint4*)part, (uint4*)t, n8);

  k_gemm2<<<2048, 256, 0, stream>>>(t, qa_h, sa, sb, bias, out);
}